// Round 6
// baseline (932.593 us; speedup 1.0000x reference)
//
#include <hip/hip_runtime.h>

#define BB 4096
#define SS 512
#define NG 256     // 4*HID gate columns
#define BT 16      // batch rows per workgroup (grid = 256 = #CUs)
#define NT 1024    // 16 waves, 4 per SIMD
#define CH 32      // time-chunk length
#define HSTR 68    // hbuf row stride (shorts)
#define PSTR 16    // pcx row stride (shorts): slots 0..11 real, 12..15 zero
#define SBSTR 264  // sbias row stride (floats), overlaid on pcx
#define GSTR 68    // gexch row stride (floats): publish/read both 2-way (free)
#define OSTR 33    // obuf row stride (floats)

typedef __bf16 bf16_t;
typedef bf16_t bf16x8 __attribute__((ext_vector_type(8)));
typedef float  f32x4  __attribute__((ext_vector_type(4)));

__device__ __forceinline__ unsigned short f2bf(float x) {
    union { float f; unsigned u; } q{x};
    unsigned r = (q.u + 0x7fffu + ((q.u >> 16) & 1u)) >> 16;
    return (unsigned short)r;
}
__device__ __forceinline__ float bf2f(unsigned short s) {
    union { unsigned u; float f; } q{((unsigned)s) << 16};
    return q.f;
}
#define LOG2E 1.4426950408889634f
__device__ __forceinline__ float frcp_(float x)  { return __builtin_amdgcn_rcpf(x); }
__device__ __forceinline__ float fexp2_(float x) { return __builtin_amdgcn_exp2f(x); }
__device__ __forceinline__ float flog2_(float x) { return __builtin_amdgcn_logf(x); }
__device__ __forceinline__ float sigmoid_(float x) { return frcp_(1.0f + fexp2_(-LOG2E * x)); }
__device__ __forceinline__ float tanh_(float x)    { return 1.0f - 2.0f * frcp_(1.0f + fexp2_((2.0f * LOG2E) * x)); }
__device__ __forceinline__ float softplus_(float x){ return x > 20.0f ? x : 0.6931471805599453f * flog2_(1.0f + fexp2_(LOG2E * x)); }

// K-slot layout (96): 0..63 = h, 64 = prev, 65..74 = cov, 75 = prev residual, 76..95 = 0.
// Wave wv = (g = wv>>2, uu = wv&3) owns gate-tile n = g*64 + uu*16 + ln.
// Step: b_h -> [reads h, 2 MFMAs on acc_pre, publish gates, prefetch a2] -> b_g ->
//       [cell: 1/(row=wv&15,unit=lane) thread, acc_pre(t+1) = mfma(a2,..,sbf), head epilogue, chunk ops]
__global__ __launch_bounds__(NT)
void deepar_kernel(const float* __restrict__ target, const float* __restrict__ cov,
                   const int* __restrict__ cats, const float* __restrict__ scale,
                   const float* __restrict__ emb0, const float* __restrict__ emb1,
                   const float* __restrict__ emb2, const float* __restrict__ emb3,
                   const float* __restrict__ w_ih, const float* __restrict__ w_hh,
                   const float* __restrict__ bias, const float* __restrict__ w_out,
                   const float* __restrict__ b_out, float* __restrict__ out)
{
    // pcx (2*32*16*16 shorts = 32768 B) overlays sbias(16896 B)+sx(4352 B) scratch
    __shared__ __attribute__((aligned(16))) unsigned char smemA[2 * CH * BT * PSTR * 2];
    __shared__ __attribute__((aligned(16))) unsigned short hbuf[2][BT][HSTR]; //  4352 B
    __shared__ float gexch[4 * BT * GSTR];                                    // 17408 B
    __shared__ float obuf[2][CH][OSTR];                                       //  8448 B
    __shared__ float inv_s[BT], scl_s[BT];

    unsigned short* pcx   = (unsigned short*)smemA;
    float*          sbias = (float*)smemA;
    float*          sx    = (float*)(smemA + BT * SBSTR * 4);

    const int tid  = threadIdx.x;
    const int b0   = blockIdx.x * BT;
    const int lane = tid & 63;
    const int wv   = tid >> 6;
    const int qd   = lane >> 4;
    const int ln   = lane & 15;
    const int g    = wv >> 2;       // gate owned by this wave
    const int uu   = wv & 3;        // unit group (units 16uu..16uu+15)

    // ---------------- setup ----------------
    for (int i = tid; i < 2 * BT * HSTR; i += NT) ((unsigned short*)hbuf)[i] = 0;
    if (tid < BT) {
        float s = scale[b0 + tid];
        scl_s[tid] = s;
        inv_s[tid] = 1.0f / fmaxf(s, 1e-4f);
        sx[tid * 68 + 64] = log1pf(s);
    }
    if (tid < BT * 4) {
        int r = tid >> 2, e = tid & 3;
        int c = cats[(b0 + r) * 4 + e];
        const float* eb = (e == 0 ? emb0 : e == 1 ? emb1 : e == 2 ? emb2 : emb3);
        for (int j = 0; j < 16; ++j) sx[r * 68 + e * 16 + j] = eb[c * 16 + j];
    }
    __syncthreads();

    // sbias[r][n] = bias[n] + static_x[r] . w_ih[11..75][n]; n = tid&255, 4 rows per thread
    {
        const int n = tid & 255, q = tid >> 8;
        float bj = bias[n];
        float acc[4];
        #pragma unroll
        for (int r = 0; r < 4; ++r) acc[r] = bj;
        for (int k = 0; k < 65; ++k) {
            float w = w_ih[(11 + k) * NG + n];
            #pragma unroll
            for (int r = 0; r < 4; ++r) acc[r] += sx[(q * 4 + r) * 68 + k] * w;
        }
        #pragma unroll
        for (int r = 0; r < 4; ++r) sbias[(q * 4 + r) * SBSTR + n] = acc[r];
    }
    __syncthreads();

    // ---------------- register-resident weights + sbias fragment (one tile per wave) ----------------
    bf16x8 bfrag[3];
    f32x4  sbf;
    {
        const int n = g * 64 + uu * 16 + ln;
        #pragma unroll
        for (int c = 0; c < 3; ++c) {
            #pragma unroll
            for (int j = 0; j < 8; ++j) {
                int k = qd * 8 + 32 * c + j;
                float w;
                if (k < 64)                  w = w_hh[k * NG + n];
                else if (k == 64 || k == 75) w = w_ih[n];
                else if (k <= 74)            w = w_ih[(k - 64) * NG + n];
                else                         w = 0.0f;
                bfrag[c][j] = (bf16_t)w;
            }
        }
        #pragma unroll
        for (int r = 0; r < 4; ++r)
            sbf[r] = sbias[(qd * 4 + r) * SBSTR + n];
    }

    // head fragments (wave 0 only uses them): B = w_out padded to 16 cols, C = b_out
    bf16x8 wob0, wob1;
    f32x4  bC;
    float  scl4[4];
    #pragma unroll
    for (int j = 0; j < 8; ++j) {
        wob0[j] = (bf16_t)((ln < 2) ? w_out[(qd * 8 + j) * 2 + ln] : 0.0f);
        wob1[j] = (bf16_t)((ln < 2) ? w_out[(32 + qd * 8 + j) * 2 + ln] : 0.0f);
    }
    #pragma unroll
    for (int r = 0; r < 4; ++r) {
        bC[r]   = (ln < 2) ? b_out[ln] : 0.0f;
        scl4[r] = (ln == 0) ? scl_s[qd * 4 + r] : 1.0f;   // mus scaled, alphas not
    }

    __syncthreads();   // all sbias/sx reads done -> safe to overwrite with pcx

    // zero pcx (both buffers; establishes the permanent-zero slots 12..15)
    for (int i = tid; i < (2 * CH * BT * PSTR) / 2; i += NT) ((int*)smemA)[i] = 0;
    __syncthreads();

    // fill pcx chunk 0 (steps 0..31)
    if (tid < 256) {
        const int row = tid >> 4, i5 = tid & 15;
        const float* cr = cov + (size_t)(b0 + row) * (SS * 10);
        #pragma unroll
        for (int j = 0; j < 20; ++j) {
            int e = i5 + 16 * j, tp = e / 10, k = e - 10 * tp;
            pcx[((0 * CH + tp) * BT + row) * PSTR + 1 + k] = f2bf(cr[e]);
        }
        float pv0 = (i5 == 0) ? 0.0f : target[(size_t)(b0 + row) * SS + i5 - 1] * inv_s[row];
        float pv1 = target[(size_t)(b0 + row) * SS + i5 + 15] * inv_s[row];
        unsigned short m0 = f2bf(pv0), m1 = f2bf(pv1);
        pcx[((0 * CH + i5) * BT + row) * PSTR + 0]       = m0;
        pcx[((0 * CH + i5) * BT + row) * PSTR + 11]      = f2bf(pv0 - bf2f(m0));
        pcx[((0 * CH + i5 + 16) * BT + row) * PSTR + 0]  = m1;
        pcx[((0 * CH + i5 + 16) * BT + row) * PSTR + 11] = f2bf(pv1 - bf2f(m1));
    }
    __syncthreads();

    // prime a2(0) and acc_pre(0) = x-part of gates for t=0
    bf16x8 a2 = {};
    if (qd < 2)
        a2 = *(const bf16x8*)&pcx[((0 * CH + 0) * BT + ln) * PSTR + qd * 8];
    f32x4 acc_pre = __builtin_amdgcn_mfma_f32_16x16x32_bf16(a2, bfrag[2], sbf, 0, 0, 0);

    float cst = 0.0f;                 // cell state for (row = wv&15, unit = lane)
    f32x4 hacc = {};
    float crg[20];
    #pragma unroll
    for (int j = 0; j < 20; ++j) crg[j] = 0.0f;
    float trg0 = 0.0f, trg1 = 0.0f;

    // ---------------- time loop (2 barriers per step) ----------------
    for (int t = 0; t < SS; ++t) {
        const int cur = t & 1, nxt = cur ^ 1;
        __syncthreads();   // b_h: hbuf[cur] complete

        // chunk start: waves 8-11 issue global loads for chunk c+1 (committed 16 steps later)
        if ((t & 31) == 0 && t < 480 && wv >= 8 && wv < 12) {
            const int tid2 = tid - 512;
            const int row = tid2 >> 4, i5 = tid2 & 15, t0n = t + CH;
            const float* cr = cov + (size_t)(b0 + row) * (SS * 10) + t0n * 10;
            #pragma unroll
            for (int j = 0; j < 20; ++j) crg[j] = cr[i5 + 16 * j];
            const float* tr = target + (size_t)(b0 + row) * SS + t0n + i5;
            trg0 = tr[-1];
            trg1 = tr[15];
        }

        // interval 1: h reads + 2 MFMAs + publish
        const unsigned short* hb = &hbuf[cur][ln][0];
        bf16x8 a0 = *(const bf16x8*)(hb + qd * 8);
        bf16x8 a1 = *(const bf16x8*)(hb + 32 + qd * 8);

        f32x4 acc = __builtin_amdgcn_mfma_f32_16x16x32_bf16(a0, bfrag[0], acc_pre, 0, 0, 0);
        acc = __builtin_amdgcn_mfma_f32_16x16x32_bf16(a1, bfrag[1], acc, 0, 0, 0);

        // head for t-1 via MFMA on wave 0 (a0/a1 ARE h_{t-1}; no ds_read, no shfl)
        if (wv == 0 && t > 0) {
            hacc = __builtin_amdgcn_mfma_f32_16x16x32_bf16(a0, wob0, bC, 0, 0, 0);
            hacc = __builtin_amdgcn_mfma_f32_16x16x32_bf16(a1, wob1, hacc, 0, 0, 0);
        }

        // publish gate accs: gexch[(g*16 + row)*GSTR + unit]  (2-way banks: free)
        {
            float* gb = gexch + (g * BT + qd * 4) * GSTR + uu * 16 + ln;
            #pragma unroll
            for (int r = 0; r < 4; ++r) gb[r * GSTR] = acc[r];
        }

        // prefetch a2 for t+1 (pcx stable; committed >=15 steps earlier)
        if (t + 1 < SS && qd < 2)
            a2 = *(const bf16x8*)&pcx[((((t + 1) >> 5) & 1) * CH + ((t + 1) & 31)) * BT * PSTR
                                      + ln * PSTR + qd * 8];

        __syncthreads();   // b_g: gexch complete

        // interval 2: one cell per thread (row = wv&15, unit = lane)
        {
            const int row = wv & 15;
            const float* gb = gexch + row * GSTR + lane;
            float gi = gb[0 * BT * GSTR];
            float gf = gb[1 * BT * GSTR];
            float gg = gb[2 * BT * GSTR];
            float go = gb[3 * BT * GSTR];
            float cc = sigmoid_(gf) * cst + sigmoid_(gi) * tanh_(gg);
            cst = cc;
            float h = sigmoid_(go) * tanh_(cc);
            *((unsigned short*)&hbuf[nxt][row][lane]) = f2bf(h);
        }

        // x-part of gates for t+1 (independent of h_t; fills interval-2 MFMA pipe)
        acc_pre = __builtin_amdgcn_mfma_f32_16x16x32_bf16(a2, bfrag[2], sbf, 0, 0, 0);

        // head epilogue: wave 0, cols 0-1 -> softplus -> obuf (rows qd*4+r)
        if (wv == 0 && t > 0 && ln < 2) {
            #pragma unroll
            for (int r = 0; r < 4; ++r) {
                float sp = softplus_(hacc[r]) + 1e-4f;
                obuf[((t - 1) >> 5) & 1][(t - 1) & 31][ln * 16 + qd * 4 + r] = sp * scl4[r];
            }
        }

        // chunk ops
        if ((t & 31) == 16) {
            const int c = t >> 5;
            if (c < 15 && wv >= 8 && wv < 12) {   // commit pcx chunk c+1 from registers
                const int tid2 = tid - 512;
                const int row = tid2 >> 4, i5 = tid2 & 15, nb = (c + 1) & 1;
                float pv0 = trg0 * inv_s[row];
                float pv1 = trg1 * inv_s[row];
                unsigned short m0 = f2bf(pv0), m1 = f2bf(pv1);
                pcx[((nb * CH + i5) * BT + row) * PSTR + 0]       = m0;
                pcx[((nb * CH + i5) * BT + row) * PSTR + 11]      = f2bf(pv0 - bf2f(m0));
                pcx[((nb * CH + i5 + 16) * BT + row) * PSTR + 0]  = m1;
                pcx[((nb * CH + i5 + 16) * BT + row) * PSTR + 11] = f2bf(pv1 - bf2f(m1));
                #pragma unroll
                for (int j = 0; j < 20; ++j) {
                    int e = i5 + 16 * j, tp = e / 10, k = e - 10 * tp;
                    pcx[((nb * CH + tp) * BT + row) * PSTR + 1 + k] = f2bf(crg[j]);
                }
            }
            if (c >= 1) {   // flush obuf chunk c-1: exactly one store per thread
                const int pb = (c - 1) & 1, t0p = (c - 1) << 5;
                const int tte = tid & 31, rowe = (tid >> 5) & 15, pe = tid >> 9;
                out[(pe ? (BB * SS) : 0) + (size_t)(b0 + rowe) * SS + t0p + tte] =
                    obuf[pb][tte][pe * 16 + rowe];
            }
        }
    }

    // ---------------- epilogue: head for t=511 (h_511 in hbuf[0]) + flush chunk 15 ----------------
    __syncthreads();
    if (wv == 0) {
        const unsigned short* hb = &hbuf[0][ln][0];
        bf16x8 a0 = *(const bf16x8*)(hb + qd * 8);
        bf16x8 a1 = *(const bf16x8*)(hb + 32 + qd * 8);
        hacc = __builtin_amdgcn_mfma_f32_16x16x32_bf16(a0, wob0, bC, 0, 0, 0);
        hacc = __builtin_amdgcn_mfma_f32_16x16x32_bf16(a1, wob1, hacc, 0, 0, 0);
        if (ln < 2) {
            #pragma unroll
            for (int r = 0; r < 4; ++r) {
                float sp = softplus_(hacc[r]) + 1e-4f;
                obuf[1][31][ln * 16 + qd * 4 + r] = sp * scl4[r];
            }
        }
    }
    __syncthreads();
    {
        const int tte = tid & 31, rowe = (tid >> 5) & 15, pe = tid >> 9;
        out[(pe ? (BB * SS) : 0) + (size_t)(b0 + rowe) * SS + 480 + tte] =
            obuf[1][tte][pe * 16 + rowe];
    }
}

extern "C" void kernel_launch(void* const* d_in, const int* in_sizes, int n_in,
                              void* d_out, int out_size, void* d_ws, size_t ws_size,
                              hipStream_t stream) {
    deepar_kernel<<<BB / BT, NT, 0, stream>>>(
        (const float*)d_in[0], (const float*)d_in[1], (const int*)d_in[2],
        (const float*)d_in[3], (const float*)d_in[4], (const float*)d_in[5],
        (const float*)d_in[6], (const float*)d_in[7], (const float*)d_in[8],
        (const float*)d_in[9], (const float*)d_in[10], (const float*)d_in[11],
        (const float*)d_in[12], (float*)d_out);
}

// Round 7
// 494.071 us; speedup vs baseline: 1.8876x; 1.8876x over previous
//
#include <hip/hip_runtime.h>

#define BB 4096
#define SS 512
#define NG 256     // 4*HID gate columns
#define BT 16      // batch rows per workgroup (grid = 256 = #CUs)
#define NT 512     // 8 waves: 0-3 compute (MFMA+cell), 4-7 service (head/stage/flush)
#define CH 32      // time-chunk length
#define HSTR 68    // hbuf row stride (shorts)
#define PSTR 16    // pcx row stride (shorts): slots 0..11 real, 12..15 zero
#define SBSTR 264  // sbias row stride (floats), overlaid on pcx
#define OSTR 33    // obuf row stride (floats)

typedef __bf16 bf16_t;
typedef bf16_t bf16x8 __attribute__((ext_vector_type(8)));
typedef float  f32x4  __attribute__((ext_vector_type(4)));

__device__ __forceinline__ unsigned short f2bf(float x) {
    union { float f; unsigned u; } q{x};
    unsigned r = (q.u + 0x7fffu + ((q.u >> 16) & 1u)) >> 16;
    return (unsigned short)r;
}
__device__ __forceinline__ float bf2f(unsigned short s) {
    union { unsigned u; float f; } q{((unsigned)s) << 16};
    return q.f;
}
#define LOG2E 1.4426950408889634f
__device__ __forceinline__ float frcp_(float x)  { return __builtin_amdgcn_rcpf(x); }
__device__ __forceinline__ float fexp2_(float x) { return __builtin_amdgcn_exp2f(x); }
__device__ __forceinline__ float flog2_(float x) { return __builtin_amdgcn_logf(x); }
__device__ __forceinline__ float softplus_(float x){ return x > 20.0f ? x : 0.6931471805599453f * flog2_(1.0f + fexp2_(LOG2E * x)); }

// K-slot layout (96): 0..63 = h, 64 = prev, 65..74 = cov, 75 = prev residual, 76..95 = 0.
// Gate columns pre-scaled: i,f,o by -log2e; g by -2log2e, so the cell needs no pre-mul:
//   sigma(x) = rcp(1+exp2(y)),  tanh(x) = 2*rcp(1+exp2(z)) - 1.
// Waves 0-3: wave wv owns all 4 gates for units 16wv..16wv+15; cell lane-local.
// Wave 4: output head via MFMA. Waves 4-7: chunk staging/flush. One barrier/step.
__global__ __launch_bounds__(NT)
void deepar_kernel(const float* __restrict__ target, const float* __restrict__ cov,
                   const int* __restrict__ cats, const float* __restrict__ scale,
                   const float* __restrict__ emb0, const float* __restrict__ emb1,
                   const float* __restrict__ emb2, const float* __restrict__ emb3,
                   const float* __restrict__ w_ih, const float* __restrict__ w_hh,
                   const float* __restrict__ bias, const float* __restrict__ w_out,
                   const float* __restrict__ b_out, float* __restrict__ out)
{
    // pcx (2*32*16*16 shorts = 32768 B) overlays sbias(16896 B)+sx(4352 B) scratch
    __shared__ __attribute__((aligned(16))) unsigned char smemA[2 * CH * BT * PSTR * 2];
    __shared__ __attribute__((aligned(16))) unsigned short hbuf[2][BT][HSTR]; //  4352 B
    __shared__ float obuf[2][CH][OSTR];                                       //  8448 B
    __shared__ float inv_s[BT], scl_s[BT];

    unsigned short* pcx   = (unsigned short*)smemA;
    float*          sbias = (float*)smemA;
    float*          sx    = (float*)(smemA + BT * SBSTR * 4);

    const int tid  = threadIdx.x;
    const int b0   = blockIdx.x * BT;
    const int lane = tid & 63;
    const int wv   = tid >> 6;
    const int qd   = lane >> 4;
    const int ln   = lane & 15;
    const bool is_compute = (wv < 4);
    const int tid2 = tid & 255;          // index within service half (wv>=4)

    // ---------------- setup ----------------
    for (int i = tid; i < 2 * BT * HSTR; i += NT) ((unsigned short*)hbuf)[i] = 0;
    if (tid < BT) {
        float s = scale[b0 + tid];
        scl_s[tid] = s;
        inv_s[tid] = 1.0f / fmaxf(s, 1e-4f);
        sx[tid * 68 + 64] = log1pf(s);
    }
    if (tid < BT * 4) {
        int r = tid >> 2, e = tid & 3;
        int c = cats[(b0 + r) * 4 + e];
        const float* eb = (e == 0 ? emb0 : e == 1 ? emb1 : e == 2 ? emb2 : emb3);
        for (int j = 0; j < 16; ++j) sx[r * 68 + e * 16 + j] = eb[c * 16 + j];
    }
    __syncthreads();

    // sbias[r][n] = bias[n] + static_x[r] . w_ih[11..75][n]; n = tid&255, rows split by tid>>8
    {
        const int n = tid & 255, half = tid >> 8;
        float bj = bias[n];
        float acc[8];
        #pragma unroll
        for (int r = 0; r < 8; ++r) acc[r] = bj;
        for (int k = 0; k < 65; ++k) {
            float w = w_ih[(11 + k) * NG + n];
            #pragma unroll
            for (int r = 0; r < 8; ++r) acc[r] += sx[(half * 8 + r) * 68 + k] * w;
        }
        #pragma unroll
        for (int r = 0; r < 8; ++r) sbias[(half * 8 + r) * SBSTR + n] = acc[r];
    }
    __syncthreads();

    // ---------------- register-resident weights + sbias fragments (compute waves) ----------------
    // gate scale factors folded into weights/bias
    bf16x8 bfrag[4][3];
    f32x4  sbf[4];
    if (is_compute) {
        #pragma unroll
        for (int ti = 0; ti < 4; ++ti) {
            const float gsc = (ti == 2) ? (-2.0f * LOG2E) : (-LOG2E);
            const int n = ln + 16 * (wv + 4 * ti);   // gate ti, unit 16wv+ln
            #pragma unroll
            for (int c = 0; c < 3; ++c) {
                #pragma unroll
                for (int j = 0; j < 8; ++j) {
                    int k = qd * 8 + 32 * c + j;
                    float w;
                    if (k < 64)                  w = w_hh[k * NG + n];
                    else if (k == 64 || k == 75) w = w_ih[n];
                    else if (k <= 74)            w = w_ih[(k - 64) * NG + n];
                    else                         w = 0.0f;
                    bfrag[ti][c][j] = (bf16_t)(w * gsc);
                }
            }
            #pragma unroll
            for (int r = 0; r < 4; ++r)
                sbf[ti][r] = sbias[(qd * 4 + r) * SBSTR + n] * gsc;
        }
    }

    // head fragments (used by wave 4): B = w_out padded to 16 cols, C = b_out
    bf16x8 wob0, wob1;
    f32x4  bC;
    float  scl4[4];
    #pragma unroll
    for (int j = 0; j < 8; ++j) {
        wob0[j] = (bf16_t)((ln < 2) ? w_out[(qd * 8 + j) * 2 + ln] : 0.0f);
        wob1[j] = (bf16_t)((ln < 2) ? w_out[(32 + qd * 8 + j) * 2 + ln] : 0.0f);
    }
    #pragma unroll
    for (int r = 0; r < 4; ++r) {
        bC[r]   = (ln < 2) ? b_out[ln] : 0.0f;
        scl4[r] = (ln == 0) ? scl_s[qd * 4 + r] : 1.0f;   // mus scaled, alphas not
    }

    __syncthreads();   // all sbias/sx reads done -> safe to overwrite with pcx

    // zero pcx (both buffers; establishes the permanent-zero slots 12..15)
    for (int i = tid; i < (2 * CH * BT * PSTR) / 2; i += NT) ((int*)smemA)[i] = 0;
    __syncthreads();

    // fill pcx chunk 0 (steps 0..31)
    if (tid < 256) {
        const int row = tid >> 4, i5 = tid & 15;
        const float* cr = cov + (size_t)(b0 + row) * (SS * 10);
        #pragma unroll
        for (int j = 0; j < 20; ++j) {
            int e = i5 + 16 * j, tp = e / 10, k = e - 10 * tp;
            pcx[((0 * CH + tp) * BT + row) * PSTR + 1 + k] = f2bf(cr[e]);
        }
        float pv0 = (i5 == 0) ? 0.0f : target[(size_t)(b0 + row) * SS + i5 - 1] * inv_s[row];
        float pv1 = target[(size_t)(b0 + row) * SS + i5 + 15] * inv_s[row];
        unsigned short m0 = f2bf(pv0), m1 = f2bf(pv1);
        pcx[((0 * CH + i5) * BT + row) * PSTR + 0]       = m0;
        pcx[((0 * CH + i5) * BT + row) * PSTR + 11]      = f2bf(pv0 - bf2f(m0));
        pcx[((0 * CH + i5 + 16) * BT + row) * PSTR + 0]  = m1;
        pcx[((0 * CH + i5 + 16) * BT + row) * PSTR + 11] = f2bf(pv1 - bf2f(m1));
    }
    __syncthreads();

    // prime a2(0) and acc_pre(0) = x-part of gates for t=0 (compute waves)
    bf16x8 a2 = {};
    f32x4 acc_pre[4];
    if (is_compute) {
        if (qd < 2)
            a2 = *(const bf16x8*)&pcx[((0 * CH + 0) * BT + ln) * PSTR + qd * 8];
        #pragma unroll
        for (int ti = 0; ti < 4; ++ti)
            acc_pre[ti] = __builtin_amdgcn_mfma_f32_16x16x32_bf16(a2, bfrag[ti][2], sbf[ti], 0, 0, 0);
    }

    float cst[4] = {0.0f, 0.0f, 0.0f, 0.0f};
    float crg[20];
    #pragma unroll
    for (int j = 0; j < 20; ++j) crg[j] = 0.0f;
    float trg0 = 0.0f, trg1 = 0.0f;

    // ---------------- time loop (ONE barrier per step) ----------------
    for (int t = 0; t < SS; ++t) {
        const int cur = t & 1, nxt = cur ^ 1;
        __syncthreads();   // hbuf[cur] complete; acc_pre already holds x-part of gates(t)

        if (is_compute) {
            // ---- recurrence waves: 2-deep MFMA chain + lane-local cell ----
            const unsigned short* hb = &hbuf[cur][ln][0];
            bf16x8 a0 = *(const bf16x8*)(hb + qd * 8);
            bf16x8 a1 = *(const bf16x8*)(hb + 32 + qd * 8);

            f32x4 acc0 = __builtin_amdgcn_mfma_f32_16x16x32_bf16(a0, bfrag[0][0], acc_pre[0], 0, 0, 0);
            f32x4 acc1 = __builtin_amdgcn_mfma_f32_16x16x32_bf16(a0, bfrag[1][0], acc_pre[1], 0, 0, 0);
            f32x4 acc2 = __builtin_amdgcn_mfma_f32_16x16x32_bf16(a0, bfrag[2][0], acc_pre[2], 0, 0, 0);
            f32x4 acc3 = __builtin_amdgcn_mfma_f32_16x16x32_bf16(a0, bfrag[3][0], acc_pre[3], 0, 0, 0);
            acc0 = __builtin_amdgcn_mfma_f32_16x16x32_bf16(a1, bfrag[0][1], acc0, 0, 0, 0);
            acc1 = __builtin_amdgcn_mfma_f32_16x16x32_bf16(a1, bfrag[1][1], acc1, 0, 0, 0);
            acc2 = __builtin_amdgcn_mfma_f32_16x16x32_bf16(a1, bfrag[2][1], acc2, 0, 0, 0);
            acc3 = __builtin_amdgcn_mfma_f32_16x16x32_bf16(a1, bfrag[3][1], acc3, 0, 0, 0);

            // prefetch a2 for t+1 (pcx stable; committed >=15 steps earlier)
            if (t + 1 < SS && qd < 2)
                a2 = *(const bf16x8*)&pcx[((((t + 1) >> 5) & 1) * CH + ((t + 1) & 31)) * BT * PSTR
                                          + ln * PSTR + qd * 8];

            // lane-local LSTM cell: unit u = 16wv+ln, rows qd*4+r
            // acc0/1/3 = -log2e * (i,f,o preact); acc2 = -2log2e * g preact
            const int u = 16 * wv + ln;
            #pragma unroll
            for (int r = 0; r < 4; ++r) {
                float si = frcp_(1.0f + fexp2_(acc0[r]));
                float sf = frcp_(1.0f + fexp2_(acc1[r]));
                float tg = 2.0f * frcp_(1.0f + fexp2_(acc2[r])) - 1.0f;
                float so = frcp_(1.0f + fexp2_(acc3[r]));
                float cc = sf * cst[r] + si * tg;
                cst[r] = cc;
                float th = 2.0f * frcp_(1.0f + fexp2_((-2.0f * LOG2E) * cc)) - 1.0f;
                *(bf16_t*)&hbuf[nxt][qd * 4 + r][u] = (bf16_t)(so * th);
            }

            // x-part of gates for t+1 (independent of h; executes under the barrier wait)
            if (t + 1 < SS) {
                #pragma unroll
                for (int ti = 0; ti < 4; ++ti)
                    acc_pre[ti] = __builtin_amdgcn_mfma_f32_16x16x32_bf16(a2, bfrag[ti][2], sbf[ti], 0, 0, 0);
            }
        } else {
            // ---- service waves ----
            if ((t & 31) == 0 && t < 480) {
                const int row = tid2 >> 4, i5 = tid2 & 15, t0n = t + CH;
                const float* cr = cov + (size_t)(b0 + row) * (SS * 10) + t0n * 10;
                #pragma unroll
                for (int j = 0; j < 20; ++j) crg[j] = cr[i5 + 16 * j];
                const float* tr = target + (size_t)(b0 + row) * SS + t0n + i5;
                trg0 = tr[-1];
                trg1 = tr[15];
            }

            // head for t-1 via MFMA on wave 4 (reads h_{t-1} fragments; no shfl chain)
            if (wv == 4 && t > 0) {
                const unsigned short* hb = &hbuf[cur][ln][0];
                bf16x8 a0 = *(const bf16x8*)(hb + qd * 8);
                bf16x8 a1 = *(const bf16x8*)(hb + 32 + qd * 8);
                f32x4 hacc = __builtin_amdgcn_mfma_f32_16x16x32_bf16(a0, wob0, bC, 0, 0, 0);
                hacc = __builtin_amdgcn_mfma_f32_16x16x32_bf16(a1, wob1, hacc, 0, 0, 0);
                if (ln < 2) {
                    #pragma unroll
                    for (int r = 0; r < 4; ++r) {
                        float sp = softplus_(hacc[r]) + 1e-4f;
                        obuf[((t - 1) >> 5) & 1][(t - 1) & 31][ln * 16 + qd * 4 + r] = sp * scl4[r];
                    }
                }
            }

            if ((t & 31) == 16) {
                const int c = t >> 5;
                if (c < 15) {
                    const int row = tid2 >> 4, i5 = tid2 & 15, nb = (c + 1) & 1;
                    float pv0 = trg0 * inv_s[row];
                    float pv1 = trg1 * inv_s[row];
                    unsigned short m0 = f2bf(pv0), m1 = f2bf(pv1);
                    pcx[((nb * CH + i5) * BT + row) * PSTR + 0]       = m0;
                    pcx[((nb * CH + i5) * BT + row) * PSTR + 11]      = f2bf(pv0 - bf2f(m0));
                    pcx[((nb * CH + i5 + 16) * BT + row) * PSTR + 0]  = m1;
                    pcx[((nb * CH + i5 + 16) * BT + row) * PSTR + 11] = f2bf(pv1 - bf2f(m1));
                    #pragma unroll
                    for (int j = 0; j < 20; ++j) {
                        int e = i5 + 16 * j, tp = e / 10, k = e - 10 * tp;
                        pcx[((nb * CH + tp) * BT + row) * PSTR + 1 + k] = f2bf(crg[j]);
                    }
                }
                if (c >= 1) {
                    const int pb = (c - 1) & 1, t0p = (c - 1) << 5;
                    #pragma unroll
                    for (int h = 0; h < 4; ++h) {
                        int e = tid2 + 256 * h;
                        int tte = e & 31, rowe = (e >> 5) & 15, pe = e >> 9;
                        out[(pe ? (BB * SS) : 0) + (size_t)(b0 + rowe) * SS + t0p + tte] =
                            obuf[pb][tte][pe * 16 + rowe];
                    }
                }
            }
        }
    }

    // ---------------- epilogue: head for t=511 (h in hbuf[0]) + flush chunk 15 ----------------
    __syncthreads();
    if (wv == 4) {
        const unsigned short* hb = &hbuf[0][ln][0];
        bf16x8 a0 = *(const bf16x8*)(hb + qd * 8);
        bf16x8 a1 = *(const bf16x8*)(hb + 32 + qd * 8);
        f32x4 hacc = __builtin_amdgcn_mfma_f32_16x16x32_bf16(a0, wob0, bC, 0, 0, 0);
        hacc = __builtin_amdgcn_mfma_f32_16x16x32_bf16(a1, wob1, hacc, 0, 0, 0);
        if (ln < 2) {
            #pragma unroll
            for (int r = 0; r < 4; ++r) {
                float sp = softplus_(hacc[r]) + 1e-4f;
                obuf[1][31][ln * 16 + qd * 4 + r] = sp * scl4[r];
            }
        }
    }
    __syncthreads();
    #pragma unroll
    for (int h = 0; h < 2; ++h) {
        int e = tid + NT * h;
        int tte = e & 31, rowe = (e >> 5) & 15, pe = e >> 9;
        out[(pe ? (BB * SS) : 0) + (size_t)(b0 + rowe) * SS + 480 + tte] =
            obuf[1][tte][pe * 16 + rowe];
    }
}

extern "C" void kernel_launch(void* const* d_in, const int* in_sizes, int n_in,
                              void* d_out, int out_size, void* d_ws, size_t ws_size,
                              hipStream_t stream) {
    deepar_kernel<<<BB / BT, NT, 0, stream>>>(
        (const float*)d_in[0], (const float*)d_in[1], (const int*)d_in[2],
        (const float*)d_in[3], (const float*)d_in[4], (const float*)d_in[5],
        (const float*)d_in[6], (const float*)d_in[7], (const float*)d_in[8],
        (const float*)d_in[9], (const float*)d_in[10], (const float*)d_in[11],
        (const float*)d_in[12], (float*)d_out);
}